// Round 1
// baseline (640.473 us; speedup 1.0000x reference)
//
#include <hip/hip_runtime.h>
#include <hip/hip_bf16.h>
#include <cfloat>

#define N_NODES 50000
#define N_EDGES 800000
#define FEAT 128
#define BATCH 2

__device__ inline float wave_red_max(float v){
  for(int m=32;m;m>>=1) v = fmaxf(v, __shfl_xor(v, m, 64));
  return v;
}
__device__ inline float wave_red_sum(float v){
  for(int m=32;m;m>>=1) v += __shfl_xor(v, m, 64);
  return v;
}

// ---------------- GEMM1: g = h @ W1, plus s_i = g.a[:F], s_j = g.a[F:] ----------------
// block 256: col = t&127, half = t>>7. Each iter: 8 rows (half h -> rows h*4..h*4+3).
__global__ __launch_bounds__(256) void k_gemm1(const float* __restrict__ h,
            const float* __restrict__ W1, const float* __restrict__ a,
            float* __restrict__ g, float* __restrict__ s_i, float* __restrict__ s_j)
{
  __shared__ float W1s[FEAT*FEAT];   // 64KB
  __shared__ float hbuf[8][FEAT];    // 4KB
  __shared__ float sred[4][8];       // per-wave partials: 4 rows x 2 scores
  int t = threadIdx.x;
  for(int i=t;i<FEAT*FEAT;i+=256) W1s[i]=W1[i];
  __syncthreads();
  int col = t & 127, half = t >> 7;
  int wid = t >> 6, lane = t & 63;
  const int ROWS_TOT = BATCH*N_NODES;
  float a_lo = a[col], a_hi = a[FEAT+col];
  for(int base = blockIdx.x*8; base < ROWS_TOT; base += gridDim.x*8){
    for(int i=t; i<8*FEAT; i+=256) hbuf[i>>7][i&127] = h[(size_t)base*FEAT + i];
    __syncthreads();
    float acc[4] = {0,0,0,0};
    int r0 = half*4;
    #pragma unroll
    for(int k=0;k<FEAT;k+=4){
      float w0 = W1s[(k+0)*FEAT+col];
      float w1 = W1s[(k+1)*FEAT+col];
      float w2 = W1s[(k+2)*FEAT+col];
      float w3 = W1s[(k+3)*FEAT+col];
      #pragma unroll
      for(int r=0;r<4;r++){
        float4 h4 = *(const float4*)&hbuf[r0+r][k];
        acc[r] = fmaf(h4.x, w0, acc[r]);
        acc[r] = fmaf(h4.y, w1, acc[r]);
        acc[r] = fmaf(h4.z, w2, acc[r]);
        acc[r] = fmaf(h4.w, w3, acc[r]);
      }
    }
    #pragma unroll
    for(int r=0;r<4;r++){
      int row = base + r0 + r;
      g[(size_t)row*FEAT + col] = acc[r];
      float pi = wave_red_sum(acc[r]*a_lo);
      float pj = wave_red_sum(acc[r]*a_hi);
      if(lane==0){ sred[wid][r*2+0]=pi; sred[wid][r*2+1]=pj; }
    }
    __syncthreads();
    if(t < 16){
      int r = t>>1, sc = t&1;
      int w0 = (r<4)?0:2;
      int rr = r & 3;
      float v = sred[w0][rr*2+sc] + sred[w0+1][rr*2+sc];
      int row = base + r;
      if(sc==0) s_i[row] = v; else s_j[row] = v;
    }
    __syncthreads();
  }
}

// ---------------- CSR build over src ----------------
__global__ void k_zero_int(int* __restrict__ p, int n){
  int i=blockIdx.x*blockDim.x+threadIdx.x; if(i<n) p[i]=0;
}
__global__ void k_hist(const int* __restrict__ src, int* __restrict__ cnt){
  int e = blockIdx.x*blockDim.x+threadIdx.x;
  if(e<N_EDGES) atomicAdd(&cnt[src[e]], 1);
}
__global__ __launch_bounds__(1024) void k_scan_a(const int* __restrict__ cnt, int* __restrict__ bsum){
  __shared__ int s[1024];
  int t=threadIdx.x; int idx = blockIdx.x*1024+t;
  s[t] = (idx<N_NODES)? cnt[idx] : 0;
  __syncthreads();
  for(int st=512; st>0; st>>=1){ if(t<st) s[t]+=s[t+st]; __syncthreads(); }
  if(t==0) bsum[blockIdx.x]=s[0];
}
__global__ void k_scan_b(int* __restrict__ bsum, int nb){   // 1 block, 64 threads
  int t=threadIdx.x;
  int v0 = (t<nb)? bsum[t] : 0;
  int v = v0;
  for(int st=1; st<64; st<<=1){
    int u = __shfl_up(v, st, 64);
    if(t>=st) v += u;
  }
  if(t<nb) bsum[t] = v - v0;   // exclusive
}
__global__ __launch_bounds__(1024) void k_scan_c(const int* __restrict__ cnt, const int* __restrict__ bsum,
                                                 int* __restrict__ off, int* __restrict__ curs){
  __shared__ int s[1024];
  int t=threadIdx.x; int idx=blockIdx.x*1024+t;
  int v=(idx<N_NODES)? cnt[idx]:0;
  s[t]=v; __syncthreads();
  for(int st=1; st<1024; st<<=1){
    int u = (t>=st)? s[t-st] : 0;
    __syncthreads();
    s[t] += u;
    __syncthreads();
  }
  if(idx<N_NODES){ int o = bsum[blockIdx.x] + s[t] - v; off[idx]=o; curs[idx]=o; }
}
__global__ void k_fill(const int* __restrict__ src, int* __restrict__ curs, int* __restrict__ eid){
  int e=blockIdx.x*blockDim.x+threadIdx.x;
  if(e<N_EDGES){ int pos = atomicAdd(&curs[src[e]],1); eid[pos]=e; }
}

// ---------------- aggregate: one wave per (node,batch); two-pass softmax + gather-FMA ----------------
__global__ __launch_bounds__(256) void k_agg(const float* __restrict__ g,
     const float* __restrict__ s_i, const float* __restrict__ s_j,
     const int* __restrict__ dst, const int* __restrict__ cnt, const int* __restrict__ off,
     const int* __restrict__ eid, float* __restrict__ hp)
{
  int widb = threadIdx.x>>6, lane = threadIdx.x&63;
  int wgid = blockIdx.x*4 + widb;
  if(wgid >= BATCH*N_NODES) return;
  int b = wgid / N_NODES, n = wgid - b*N_NODES;
  int deg = cnt[n], o0 = off[n];
  float sin_n = s_i[(size_t)b*N_NODES + n];
  const float* sjb = s_j + (size_t)b*N_NODES;
  const float2* gb = (const float2*)g + (size_t)b*N_NODES*64;

  // pass A: segment max
  float ml = -FLT_MAX;
  for(int base=0; base<deg; base+=64){
    int i = base+lane;
    if(i<deg){
      int e = eid[o0+i];
      float x = sin_n + sjb[dst[e]];
      x = (x>0.f)? x : 0.2f*x;
      ml = fmaxf(ml, x);
    }
  }
  float m = wave_red_max(ml);

  // pass B: exp, denom, accumulate messages
  float dl = 0.f;
  float2 acc = make_float2(0.f, 0.f);
  for(int base=0; base<deg; base+=64){
    int i = base+lane;
    int d = 0; float p = 0.f;
    if(i<deg){
      int e = eid[o0+i];
      d = dst[e];
      float x = sin_n + sjb[d];
      x = (x>0.f)? x : 0.2f*x;
      p = __expf(x - m);
      dl += p;
    }
    int lim = min(64, deg-base);
    for(int j=0;j<lim;j++){
      float pj = __shfl(p, j, 64);
      int   dj = __shfl(d, j, 64);
      float2 grow = gb[(size_t)dj*64 + lane];
      acc.x = fmaf(pj, grow.x, acc.x);
      acc.y = fmaf(pj, grow.y, acc.y);
    }
  }
  float denom = wave_red_sum(dl);
  float inv = (denom>0.f)? 1.0f/denom : 0.f;
  ((float2*)hp)[(size_t)wgid*64 + lane] = make_float2(acc.x*inv, acc.y*inv);
}

// ---------------- GEMM2 (in-place on d_out): out = relu(hp @ W2) ----------------
__global__ __launch_bounds__(256) void k_gemm2(const float* __restrict__ W2, float* __restrict__ io)
{
  __shared__ float W2s[FEAT*FEAT];
  __shared__ float hbuf[8][FEAT];
  int t=threadIdx.x;
  for(int i=t;i<FEAT*FEAT;i+=256) W2s[i]=W2[i];
  __syncthreads();
  int col=t&127, half=t>>7;
  const int ROWS_TOT=BATCH*N_NODES;
  for(int base=blockIdx.x*8; base<ROWS_TOT; base+=gridDim.x*8){
    for(int i=t;i<8*FEAT;i+=256) hbuf[i>>7][i&127]=io[(size_t)base*FEAT+i];
    __syncthreads();
    float acc[4]={0,0,0,0};
    int r0=half*4;
    #pragma unroll
    for(int k=0;k<FEAT;k+=4){
      float w0=W2s[(k+0)*FEAT+col], w1=W2s[(k+1)*FEAT+col];
      float w2=W2s[(k+2)*FEAT+col], w3=W2s[(k+3)*FEAT+col];
      #pragma unroll
      for(int r=0;r<4;r++){
        float4 h4=*(const float4*)&hbuf[r0+r][k];
        acc[r]=fmaf(h4.x,w0,acc[r]); acc[r]=fmaf(h4.y,w1,acc[r]);
        acc[r]=fmaf(h4.z,w2,acc[r]); acc[r]=fmaf(h4.w,w3,acc[r]);
      }
    }
    __syncthreads();   // all hbuf reads done before in-place writes / next load
    #pragma unroll
    for(int r=0;r<4;r++){
      io[(size_t)(base+r0+r)*FEAT+col] = fmaxf(acc[r], 0.f);
    }
    __syncthreads();
  }
}

extern "C" void kernel_launch(void* const* d_in, const int* in_sizes, int n_in,
                              void* d_out, int out_size, void* d_ws, size_t ws_size,
                              hipStream_t stream) {
  const float* h  = (const float*)d_in[0];
  const float* W1 = (const float*)d_in[1];
  const float* W2 = (const float*)d_in[2];
  const float* a  = (const float*)d_in[3];
  const int* src  = (const int*)d_in[4];
  const int* dst  = (const int*)d_in[5];
  float* out = (float*)d_out;

  float* g   = (float*)d_ws;                               // B*N*F
  float* s_i = g + (size_t)BATCH*N_NODES*FEAT;             // B*N
  float* s_j = s_i + (size_t)BATCH*N_NODES;                // B*N
  int* cnt  = (int*)(s_j + (size_t)BATCH*N_NODES);         // N
  int* off  = cnt + N_NODES;                               // N
  int* curs = off + N_NODES;                               // N
  int* eid  = curs + N_NODES;                              // E
  int* bsum = eid + N_EDGES;                               // ~64

  k_gemm1<<<1024,256,0,stream>>>(h,W1,a,g,s_i,s_j);

  k_zero_int<<<(N_NODES+255)/256,256,0,stream>>>(cnt,N_NODES);
  k_hist<<<(N_EDGES+255)/256,256,0,stream>>>(src,cnt);
  int nb=(N_NODES+1023)/1024;
  k_scan_a<<<nb,1024,0,stream>>>(cnt,bsum);
  k_scan_b<<<1,64,0,stream>>>(bsum,nb);
  k_scan_c<<<nb,1024,0,stream>>>(cnt,bsum,off,curs);
  k_fill<<<(N_EDGES+255)/256,256,0,stream>>>(src,curs,eid);

  k_agg<<<(BATCH*N_NODES+3)/4,256,0,stream>>>(g,s_i,s_j,dst,cnt,off,eid,out);
  k_gemm2<<<1024,256,0,stream>>>(W2,out);
}

// Round 2
// 264.020 us; speedup vs baseline: 2.4258x; 2.4258x over previous
//
#include <hip/hip_runtime.h>
#include <hip/hip_bf16.h>
#include <cfloat>

#define N_NODES 50000
#define N_EDGES 800000
#define FEAT 128
#define BATCH 2
#define RTOT (BATCH*N_NODES)

typedef __bf16 bf16x8 __attribute__((ext_vector_type(8)));
typedef float  f32x4  __attribute__((ext_vector_type(4)));

__device__ inline float wave_red_max(float v){
  for(int m=32;m;m>>=1) v = fmaxf(v, __shfl_xor(v, m, 64));
  return v;
}
__device__ inline float wave_red_sum(float v){
  for(int m=32;m;m>>=1) v += __shfl_xor(v, m, 64);
  return v;
}
__device__ inline unsigned short f2bf(float f){
  unsigned int u = __float_as_uint(f);
  u = (u + 0x7fffu + ((u >> 16) & 1u)) >> 16;
  return (unsigned short)u;
}

// ---- prep: W1t/W2t = bf16(W^T), pre-swizzled so linear LDS copy yields swizzled tile ----
// ushort index: SW(col,k) = col*128 + (k ^ ((col&7)<<3))
__global__ void k_prep(const float* __restrict__ W1, const float* __restrict__ W2,
                       __bf16* __restrict__ W1t, __bf16* __restrict__ W2t){
  int i = blockIdx.x*blockDim.x + threadIdx.x;
  if(i < FEAT*FEAT){
    int k = i >> 7, col = i & 127;
    int sw = (col << 7) + (k ^ ((col & 7) << 3));
    W1t[sw] = (__bf16)W1[i];
    W2t[sw] = (__bf16)W2[i];
  }
}

// ---- GEMM1 (MFMA): g = bf16(h @ W1), s_i = g@a[:F], s_j = g@a[F:] ----
// block 256 = 4 waves; wave handles 16 rows x 128 cols; K=128 in 4 steps of 32.
__global__ __launch_bounds__(256) void k_gemm1_mfma(const float* __restrict__ h,
        const __bf16* __restrict__ W1t, const float* __restrict__ a,
        __bf16* __restrict__ g, float* __restrict__ s_i, float* __restrict__ s_j)
{
  __shared__ __bf16 Bs[FEAT*FEAT];   // 32KB, swizzled W^T
  int t = threadIdx.x, lane = t & 63, wid = t >> 6;
  {
    const float4* srcp = (const float4*)W1t;
    float4* dstp = (float4*)Bs;
    for(int i = t; i < FEAT*FEAT/8; i += 256) dstp[i] = srcp[i];
  }
  __syncthreads();

  int rb = blockIdx.x*64 + wid*16;
  int r  = rb + (lane & 15);
  int kq = (lane >> 4) * 8;

  bf16x8 af[4];
  if(r < RTOT){
    const float* hrow = h + (size_t)r*FEAT + kq;
    #pragma unroll
    for(int ks = 0; ks < 4; ks++){
      float4 p0 = *(const float4*)(hrow + ks*32);
      float4 p1 = *(const float4*)(hrow + ks*32 + 4);
      bf16x8 v;
      v[0]=(__bf16)p0.x; v[1]=(__bf16)p0.y; v[2]=(__bf16)p0.z; v[3]=(__bf16)p0.w;
      v[4]=(__bf16)p1.x; v[5]=(__bf16)p1.y; v[6]=(__bf16)p1.z; v[7]=(__bf16)p1.w;
      af[ks] = v;
    }
  } else {
    #pragma unroll
    for(int ks = 0; ks < 4; ks++){ bf16x8 z = {}; af[ks] = z; }
  }

  f32x4 acc[8] = {};
  #pragma unroll
  for(int cb = 0; cb < 8; cb++){
    int col = cb*16 + (lane & 15);
    int swbase = (col << 7);
    int swx = ((col & 7) << 3);
    #pragma unroll
    for(int ks = 0; ks < 4; ks++){
      int kb = ks*32 + kq;
      bf16x8 bf = *(const bf16x8*)&Bs[swbase + (kb ^ swx)];
      acc[cb] = __builtin_amdgcn_mfma_f32_16x16x32_bf16(af[ks], bf, acc[cb], 0, 0, 0);
    }
  }

  // epilogue: store g (bf16) + score partials
  int hgrp = lane >> 4;
  float pi[4] = {0,0,0,0}, pj[4] = {0,0,0,0};
  #pragma unroll
  for(int cb = 0; cb < 8; cb++){
    int col = cb*16 + (lane & 15);
    float al = a[col], ah = a[FEAT + col];
    #pragma unroll
    for(int reg = 0; reg < 4; reg++){
      int row = rb + hgrp*4 + reg;
      float v = acc[cb][reg];
      if(row < RTOT) g[(size_t)row*FEAT + col] = (__bf16)v;
      pi[reg] = fmaf(v, al, pi[reg]);
      pj[reg] = fmaf(v, ah, pj[reg]);
    }
  }
  #pragma unroll
  for(int reg = 0; reg < 4; reg++){
    #pragma unroll
    for(int m = 1; m < 16; m <<= 1){
      pi[reg] += __shfl_xor(pi[reg], m, 64);
      pj[reg] += __shfl_xor(pj[reg], m, 64);
    }
  }
  if((lane & 15) == 0){
    #pragma unroll
    for(int reg = 0; reg < 4; reg++){
      int row = rb + hgrp*4 + reg;
      if(row < RTOT){ s_i[row] = pi[reg]; s_j[row] = pj[reg]; }
    }
  }
}

// ---- GEMM2 (MFMA): out = relu(hp @ W2), hp bf16, out fp32 ----
__global__ __launch_bounds__(256) void k_gemm2_mfma(const __bf16* __restrict__ hp,
        const __bf16* __restrict__ W2t, float* __restrict__ out)
{
  __shared__ __bf16 Bs[FEAT*FEAT];
  int t = threadIdx.x, lane = t & 63, wid = t >> 6;
  {
    const float4* srcp = (const float4*)W2t;
    float4* dstp = (float4*)Bs;
    for(int i = t; i < FEAT*FEAT/8; i += 256) dstp[i] = srcp[i];
  }
  __syncthreads();

  int rb = blockIdx.x*64 + wid*16;
  int r  = rb + (lane & 15);
  int kq = (lane >> 4) * 8;

  bf16x8 af[4];
  if(r < RTOT){
    const __bf16* hrow = hp + (size_t)r*FEAT + kq;
    #pragma unroll
    for(int ks = 0; ks < 4; ks++) af[ks] = *(const bf16x8*)(hrow + ks*32);
  } else {
    #pragma unroll
    for(int ks = 0; ks < 4; ks++){ bf16x8 z = {}; af[ks] = z; }
  }

  f32x4 acc[8] = {};
  #pragma unroll
  for(int cb = 0; cb < 8; cb++){
    int col = cb*16 + (lane & 15);
    int swbase = (col << 7);
    int swx = ((col & 7) << 3);
    #pragma unroll
    for(int ks = 0; ks < 4; ks++){
      int kb = ks*32 + kq;
      bf16x8 bf = *(const bf16x8*)&Bs[swbase + (kb ^ swx)];
      acc[cb] = __builtin_amdgcn_mfma_f32_16x16x32_bf16(af[ks], bf, acc[cb], 0, 0, 0);
    }
  }

  int hgrp = lane >> 4;
  #pragma unroll
  for(int cb = 0; cb < 8; cb++){
    int col = cb*16 + (lane & 15);
    #pragma unroll
    for(int reg = 0; reg < 4; reg++){
      int row = rb + hgrp*4 + reg;
      if(row < RTOT) out[(size_t)row*FEAT + col] = fmaxf(acc[cb][reg], 0.f);
    }
  }
}

// ---------------- CSR build over src ----------------
__global__ void k_zero_int(int* __restrict__ p, int n){
  int i=blockIdx.x*blockDim.x+threadIdx.x; if(i<n) p[i]=0;
}
__global__ void k_hist(const int* __restrict__ src, int* __restrict__ cnt){
  int e = blockIdx.x*blockDim.x+threadIdx.x;
  if(e<N_EDGES) atomicAdd(&cnt[src[e]], 1);
}
__global__ __launch_bounds__(1024) void k_scan_a(const int* __restrict__ cnt, int* __restrict__ bsum){
  __shared__ int s[1024];
  int t=threadIdx.x; int idx = blockIdx.x*1024+t;
  s[t] = (idx<N_NODES)? cnt[idx] : 0;
  __syncthreads();
  for(int st=512; st>0; st>>=1){ if(t<st) s[t]+=s[t+st]; __syncthreads(); }
  if(t==0) bsum[blockIdx.x]=s[0];
}
__global__ void k_scan_b(int* __restrict__ bsum, int nb){   // 1 block, 64 threads
  int t=threadIdx.x;
  int v0 = (t<nb)? bsum[t] : 0;
  int v = v0;
  for(int st=1; st<64; st<<=1){
    int u = __shfl_up(v, st, 64);
    if(t>=st) v += u;
  }
  if(t<nb) bsum[t] = v - v0;   // exclusive
}
__global__ __launch_bounds__(1024) void k_scan_c(const int* __restrict__ cnt, const int* __restrict__ bsum,
                                                 int* __restrict__ off, int* __restrict__ curs){
  __shared__ int s[1024];
  int t=threadIdx.x; int idx=blockIdx.x*1024+t;
  int v=(idx<N_NODES)? cnt[idx]:0;
  s[t]=v; __syncthreads();
  for(int st=1; st<1024; st<<=1){
    int u = (t>=st)? s[t-st] : 0;
    __syncthreads();
    s[t] += u;
    __syncthreads();
  }
  if(idx<N_NODES){ int o = bsum[blockIdx.x] + s[t] - v; off[idx]=o; curs[idx]=o; }
}
__global__ void k_fill(const int* __restrict__ src, int* __restrict__ curs, int* __restrict__ eid){
  int e=blockIdx.x*blockDim.x+threadIdx.x;
  if(e<N_EDGES){ int pos = atomicAdd(&curs[src[e]],1); eid[pos]=e; }
}

// ---- aggregate: one wave per (node,batch); two-pass softmax + bf16 gather-FMA ----
__global__ __launch_bounds__(256) void k_agg(const unsigned int* __restrict__ g,
     const float* __restrict__ s_i, const float* __restrict__ s_j,
     const int* __restrict__ dst, const int* __restrict__ cnt, const int* __restrict__ off,
     const int* __restrict__ eid, unsigned int* __restrict__ hp)
{
  int widb = threadIdx.x>>6, lane = threadIdx.x&63;
  int wgid = blockIdx.x*4 + widb;
  if(wgid >= RTOT) return;
  int b = wgid / N_NODES, n = wgid - b*N_NODES;
  int deg = cnt[n], o0 = off[n];
  float sin_n = s_i[(size_t)b*N_NODES + n];
  const float* sjb = s_j + (size_t)b*N_NODES;
  const unsigned int* gb = g + (size_t)b*N_NODES*64;

  float ml = -FLT_MAX;
  for(int base=0; base<deg; base+=64){
    int i = base+lane;
    if(i<deg){
      int e = eid[o0+i];
      float x = sin_n + sjb[dst[e]];
      x = (x>0.f)? x : 0.2f*x;
      ml = fmaxf(ml, x);
    }
  }
  float m = wave_red_max(ml);

  float dl = 0.f;
  float accx = 0.f, accy = 0.f;
  for(int base=0; base<deg; base+=64){
    int i = base+lane;
    int d = 0; float p = 0.f;
    if(i<deg){
      int e = eid[o0+i];
      d = dst[e];
      float x = sin_n + sjb[d];
      x = (x>0.f)? x : 0.2f*x;
      p = __expf(x - m);
      dl += p;
    }
    int lim = min(64, deg-base);
    for(int j=0;j<lim;j++){
      float pj = __shfl(p, j, 64);
      int   dj = __shfl(d, j, 64);
      unsigned int u = gb[(size_t)dj*64 + lane];
      float glo = __uint_as_float(u << 16);
      float ghi = __uint_as_float(u & 0xffff0000u);
      accx = fmaf(pj, glo, accx);
      accy = fmaf(pj, ghi, accy);
    }
  }
  float denom = wave_red_sum(dl);
  float inv = (denom>0.f)? 1.0f/denom : 0.f;
  unsigned int lo = f2bf(accx*inv);
  unsigned int hi = f2bf(accy*inv);
  hp[(size_t)wgid*64 + lane] = (hi << 16) | lo;
}

extern "C" void kernel_launch(void* const* d_in, const int* in_sizes, int n_in,
                              void* d_out, int out_size, void* d_ws, size_t ws_size,
                              hipStream_t stream) {
  const float* h  = (const float*)d_in[0];
  const float* W1 = (const float*)d_in[1];
  const float* W2 = (const float*)d_in[2];
  const float* a  = (const float*)d_in[3];
  const int* src  = (const int*)d_in[4];
  const int* dst  = (const int*)d_in[5];
  float* out = (float*)d_out;

  char* w = (char*)d_ws;
  __bf16* g   = (__bf16*)w;                          w += (size_t)RTOT*FEAT*2;   // 25.6MB
  __bf16* hp  = (__bf16*)w;                          w += (size_t)RTOT*FEAT*2;   // 25.6MB
  float* s_i  = (float*)w;                           w += (size_t)RTOT*4;
  float* s_j  = (float*)w;                           w += (size_t)RTOT*4;
  __bf16* W1t = (__bf16*)w;                          w += FEAT*FEAT*2;
  __bf16* W2t = (__bf16*)w;                          w += FEAT*FEAT*2;
  int* cnt  = (int*)w;                               w += N_NODES*4;
  int* off  = (int*)w;                               w += N_NODES*4;
  int* curs = (int*)w;                               w += N_NODES*4;
  int* eid  = (int*)w;                               w += N_EDGES*4;
  int* bsum = (int*)w;

  k_prep<<<(FEAT*FEAT+255)/256,256,0,stream>>>(W1,W2,W1t,W2t);

  int gemm_grid = (RTOT + 63)/64;
  k_gemm1_mfma<<<gemm_grid,256,0,stream>>>(h,W1t,a,g,s_i,s_j);

  k_zero_int<<<(N_NODES+255)/256,256,0,stream>>>(cnt,N_NODES);
  k_hist<<<(N_EDGES+255)/256,256,0,stream>>>(src,cnt);
  int nb=(N_NODES+1023)/1024;
  k_scan_a<<<nb,1024,0,stream>>>(cnt,bsum);
  k_scan_b<<<1,64,0,stream>>>(bsum,nb);
  k_scan_c<<<nb,1024,0,stream>>>(cnt,bsum,off,curs);
  k_fill<<<(N_EDGES+255)/256,256,0,stream>>>(src,curs,eid);

  k_agg<<<(RTOT+3)/4,256,0,stream>>>((const unsigned int*)g,s_i,s_j,dst,cnt,off,eid,(unsigned int*)hp);

  k_gemm2_mfma<<<gemm_grid,256,0,stream>>>(hp,W2t,out);
}

// Round 3
// 200.121 us; speedup vs baseline: 3.2004x; 1.3193x over previous
//
#include <hip/hip_runtime.h>
#include <hip/hip_bf16.h>
#include <cfloat>

#define N_NODES 50000
#define N_EDGES 800000
#define FEAT 128
#define BATCH 2
#define RTOT (BATCH*N_NODES)

typedef __bf16 bf16x8 __attribute__((ext_vector_type(8)));
typedef float  f32x4  __attribute__((ext_vector_type(4)));

__device__ inline unsigned short f2bf(float f){
  unsigned int u = __float_as_uint(f);
  u = (u + 0x7fffu + ((u >> 16) & 1u)) >> 16;
  return (unsigned short)u;
}

// ---- prep: W1t/W2t = bf16(W^T) pre-swizzled; also zero cnt ----
__global__ void k_prep(const float* __restrict__ W1, const float* __restrict__ W2,
                       __bf16* __restrict__ W1t, __bf16* __restrict__ W2t,
                       int* __restrict__ cnt){
  int i = blockIdx.x*blockDim.x + threadIdx.x;
  if(i < FEAT*FEAT){
    int k = i >> 7, col = i & 127;
    int sw = (col << 7) + (k ^ ((col & 7) << 3));
    W1t[sw] = (__bf16)W1[i];
    W2t[sw] = (__bf16)W2[i];
  }
  if(i < N_NODES) cnt[i] = 0;
}

// ---- GEMM1 (MFMA): g[n][b][128] = bf16(h @ W1), s_i/s_j[n][b] ----
__global__ __launch_bounds__(256) void k_gemm1_mfma(const float* __restrict__ h,
        const __bf16* __restrict__ W1t, const float* __restrict__ a,
        __bf16* __restrict__ g, float* __restrict__ s_i, float* __restrict__ s_j)
{
  __shared__ __bf16 Bs[FEAT*FEAT];   // 32KB swizzled W^T
  int t = threadIdx.x, lane = t & 63, wid = t >> 6;
  {
    const float4* srcp = (const float4*)W1t;
    float4* dstp = (float4*)Bs;
    for(int i = t; i < FEAT*FEAT/8; i += 256) dstp[i] = srcp[i];
  }
  __syncthreads();

  int rb = blockIdx.x*64 + wid*16;
  int r  = rb + (lane & 15);
  int kq = (lane >> 4) * 8;

  bf16x8 af[4];
  if(r < RTOT){
    const float* hrow = h + (size_t)r*FEAT + kq;
    #pragma unroll
    for(int ks = 0; ks < 4; ks++){
      float4 p0 = *(const float4*)(hrow + ks*32);
      float4 p1 = *(const float4*)(hrow + ks*32 + 4);
      bf16x8 v;
      v[0]=(__bf16)p0.x; v[1]=(__bf16)p0.y; v[2]=(__bf16)p0.z; v[3]=(__bf16)p0.w;
      v[4]=(__bf16)p1.x; v[5]=(__bf16)p1.y; v[6]=(__bf16)p1.z; v[7]=(__bf16)p1.w;
      af[ks] = v;
    }
  } else {
    #pragma unroll
    for(int ks = 0; ks < 4; ks++){ bf16x8 z = {}; af[ks] = z; }
  }

  f32x4 acc[8] = {};
  #pragma unroll
  for(int cb = 0; cb < 8; cb++){
    int col = cb*16 + (lane & 15);
    int swbase = (col << 7);
    int swx = ((col & 7) << 3);
    #pragma unroll
    for(int ks = 0; ks < 4; ks++){
      int kb = ks*32 + kq;
      bf16x8 bf = *(const bf16x8*)&Bs[swbase + (kb ^ swx)];
      acc[cb] = __builtin_amdgcn_mfma_f32_16x16x32_bf16(af[ks], bf, acc[cb], 0, 0, 0);
    }
  }

  int hgrp = lane >> 4;
  float pi[4] = {0,0,0,0}, pj[4] = {0,0,0,0};
  #pragma unroll
  for(int cb = 0; cb < 8; cb++){
    int col = cb*16 + (lane & 15);
    float al = a[col], ah = a[FEAT + col];
    #pragma unroll
    for(int reg = 0; reg < 4; reg++){
      int row = rb + hgrp*4 + reg;
      float v = acc[cb][reg];
      if(row < RTOT){
        int b = (row >= N_NODES) ? 1 : 0;
        int n = row - b*N_NODES;
        g[(size_t)n*256 + b*128 + col] = (__bf16)v;   // interleaved [n][b][128]
      }
      pi[reg] = fmaf(v, al, pi[reg]);
      pj[reg] = fmaf(v, ah, pj[reg]);
    }
  }
  #pragma unroll
  for(int reg = 0; reg < 4; reg++){
    #pragma unroll
    for(int m = 1; m < 16; m <<= 1){
      pi[reg] += __shfl_xor(pi[reg], m, 64);
      pj[reg] += __shfl_xor(pj[reg], m, 64);
    }
  }
  if((lane & 15) == 0){
    #pragma unroll
    for(int reg = 0; reg < 4; reg++){
      int row = rb + hgrp*4 + reg;
      if(row < RTOT){
        int b = (row >= N_NODES) ? 1 : 0;
        int n = row - b*N_NODES;
        s_i[n*2 + b] = pi[reg];
        s_j[n*2 + b] = pj[reg];
      }
    }
  }
}

// ---------------- CSR build over src ----------------
__global__ void k_hist(const int* __restrict__ src, int* __restrict__ cnt){
  int e = blockIdx.x*blockDim.x+threadIdx.x;
  if(e<N_EDGES) atomicAdd(&cnt[src[e]], 1);
}
__global__ __launch_bounds__(1024) void k_scan_a(const int* __restrict__ cnt, int* __restrict__ bsum){
  __shared__ int s[1024];
  int t=threadIdx.x; int idx = blockIdx.x*1024+t;
  s[t] = (idx<N_NODES)? cnt[idx] : 0;
  __syncthreads();
  for(int st=512; st>0; st>>=1){ if(t<st) s[t]+=s[t+st]; __syncthreads(); }
  if(t==0) bsum[blockIdx.x]=s[0];
}
__global__ void k_scan_b(int* __restrict__ bsum, int nb){   // 1 block, 64 threads
  int t=threadIdx.x;
  int v0 = (t<nb)? bsum[t] : 0;
  int v = v0;
  for(int st=1; st<64; st<<=1){
    int u = __shfl_up(v, st, 64);
    if(t>=st) v += u;
  }
  if(t<nb) bsum[t] = v - v0;   // exclusive
}
__global__ __launch_bounds__(1024) void k_scan_c(const int* __restrict__ cnt, const int* __restrict__ bsum,
                                                 int* __restrict__ off, int* __restrict__ curs){
  __shared__ int s[1024];
  int t=threadIdx.x; int idx=blockIdx.x*1024+t;
  int v=(idx<N_NODES)? cnt[idx]:0;
  s[t]=v; __syncthreads();
  for(int st=1; st<1024; st<<=1){
    int u = (t>=st)? s[t-st] : 0;
    __syncthreads();
    s[t] += u;
    __syncthreads();
  }
  if(idx<N_NODES){ int o = bsum[blockIdx.x] + s[t] - v; off[idx]=o; curs[idx]=o; }
}
// store dst VALUES in CSR order (kills the eid->dst indirection in k_agg)
__global__ void k_fill(const int* __restrict__ src, const int* __restrict__ dst,
                       int* __restrict__ curs, int* __restrict__ dste){
  int e=blockIdx.x*blockDim.x+threadIdx.x;
  if(e<N_EDGES){ int pos = atomicAdd(&curs[src[e]],1); dste[pos]=dst[e]; }
}

// ---- aggregate: one wave per node, both batches fused, online softmax ----
// lanes 0-31: batch0 (lane li covers feats 4*li..4*li+3); lanes 32-63: batch1.
__global__ __launch_bounds__(256) void k_agg(const unsigned int* __restrict__ g,
     const float* __restrict__ s_i, const float* __restrict__ s_j,
     const int* __restrict__ cnt, const int* __restrict__ off,
     const int* __restrict__ dste, unsigned int* __restrict__ hp)
{
  int widb = threadIdx.x>>6, lane = threadIdx.x&63;
  int n = blockIdx.x*4 + widb;
  if(n >= N_NODES) return;
  int deg = cnt[n], o0 = off[n];
  int half = lane >> 5, li = lane & 31;
  float si = s_i[n*2 + half];
  int selp = lane & 32;

  float m = -FLT_MAX, denom = 0.f;
  float a0=0.f, a1=0.f, a2=0.f, a3=0.f;

  for(int base=0; base<deg; base+=32){
    int i = base + li;
    int d = 0; float x = -FLT_MAX;
    if(i < deg){
      d = dste[o0 + i];                       // coalesced segment read
      float xx = si + s_j[d*2 + half];        // scattered 4B gather
      x = (xx > 0.f) ? xx : 0.2f*xx;
    }
    // per-half max reduce (masks <=16 stay within each 32-lane half)
    float cm = x;
    #pragma unroll
    for(int mm=16; mm; mm>>=1) cm = fmaxf(cm, __shfl_xor(cm, mm, 64));
    float mn = fmaxf(m, cm);
    float scale = __expf(m - mn);             // first chunk: exp(-inf)=0
    float p = (i < deg) ? __expf(x - mn) : 0.f;
    denom = denom*scale + p;
    a0*=scale; a1*=scale; a2*=scale; a3*=scale;
    m = mn;

    int lim = min(32, deg-base);
    for(int j=0;j<lim;j++){
      float pj = __shfl(p, selp | j, 64);     // own half's weight
      int   dj = __shfl(d, j, 64);            // dst node (dup'd across halves)
      uint2 u = *(const uint2*)(g + (size_t)dj*128 + lane*2);  // 512B/row/edge
      a0 = fmaf(pj, __uint_as_float(u.x << 16),         a0);
      a1 = fmaf(pj, __uint_as_float(u.x & 0xffff0000u), a1);
      a2 = fmaf(pj, __uint_as_float(u.y << 16),         a2);
      a3 = fmaf(pj, __uint_as_float(u.y & 0xffff0000u), a3);
    }
  }
  #pragma unroll
  for(int mm=16; mm; mm>>=1) denom += __shfl_xor(denom, mm, 64);
  float inv = (denom > 0.f) ? 1.0f/denom : 0.f;
  unsigned int w0 = ((unsigned int)f2bf(a1*inv) << 16) | f2bf(a0*inv);
  unsigned int w1 = ((unsigned int)f2bf(a3*inv) << 16) | f2bf(a2*inv);
  uint2 o; o.x = w0; o.y = w1;
  *(uint2*)(hp + (size_t)n*128 + lane*2) = o;
}

// ---- GEMM2 (MFMA): out[b*N+n] = relu(hp_interleaved @ W2) ----
__global__ __launch_bounds__(256) void k_gemm2_mfma(const __bf16* __restrict__ hp,
        const __bf16* __restrict__ W2t, float* __restrict__ out)
{
  __shared__ __bf16 Bs[FEAT*FEAT];
  int t = threadIdx.x, lane = t & 63, wid = t >> 6;
  {
    const float4* srcp = (const float4*)W2t;
    float4* dstp = (float4*)Bs;
    for(int i = t; i < FEAT*FEAT/8; i += 256) dstp[i] = srcp[i];
  }
  __syncthreads();

  int rb = blockIdx.x*64 + wid*16;   // interleaved row index ri = n*2+b
  int r  = rb + (lane & 15);
  int kq = (lane >> 4) * 8;

  bf16x8 af[4];
  if(r < RTOT){
    const __bf16* hrow = hp + (size_t)r*FEAT + kq;
    #pragma unroll
    for(int ks = 0; ks < 4; ks++) af[ks] = *(const bf16x8*)(hrow + ks*32);
  } else {
    #pragma unroll
    for(int ks = 0; ks < 4; ks++){ bf16x8 z = {}; af[ks] = z; }
  }

  f32x4 acc[8] = {};
  #pragma unroll
  for(int cb = 0; cb < 8; cb++){
    int col = cb*16 + (lane & 15);
    int swbase = (col << 7);
    int swx = ((col & 7) << 3);
    #pragma unroll
    for(int ks = 0; ks < 4; ks++){
      int kb = ks*32 + kq;
      bf16x8 bf = *(const bf16x8*)&Bs[swbase + (kb ^ swx)];
      acc[cb] = __builtin_amdgcn_mfma_f32_16x16x32_bf16(af[ks], bf, acc[cb], 0, 0, 0);
    }
  }

  int hgrp = lane >> 4;
  #pragma unroll
  for(int cb = 0; cb < 8; cb++){
    int col = cb*16 + (lane & 15);
    #pragma unroll
    for(int reg = 0; reg < 4; reg++){
      int ri = rb + hgrp*4 + reg;
      if(ri < RTOT){
        int orow = (ri & 1)*N_NODES + (ri >> 1);   // de-interleave
        out[(size_t)orow*FEAT + col] = fmaxf(acc[cb][reg], 0.f);
      }
    }
  }
}

extern "C" void kernel_launch(void* const* d_in, const int* in_sizes, int n_in,
                              void* d_out, int out_size, void* d_ws, size_t ws_size,
                              hipStream_t stream) {
  const float* h  = (const float*)d_in[0];
  const float* W1 = (const float*)d_in[1];
  const float* W2 = (const float*)d_in[2];
  const float* a  = (const float*)d_in[3];
  const int* src  = (const int*)d_in[4];
  const int* dst  = (const int*)d_in[5];
  float* out = (float*)d_out;

  char* w = (char*)d_ws;
  __bf16* g   = (__bf16*)w;                          w += (size_t)RTOT*FEAT*2;   // 25.6MB interleaved
  __bf16* hp  = (__bf16*)w;                          w += (size_t)RTOT*FEAT*2;   // 25.6MB interleaved
  float* s_i  = (float*)w;                           w += (size_t)RTOT*4;
  float* s_j  = (float*)w;                           w += (size_t)RTOT*4;
  __bf16* W1t = (__bf16*)w;                          w += FEAT*FEAT*2;
  __bf16* W2t = (__bf16*)w;                          w += FEAT*FEAT*2;
  int* cnt  = (int*)w;                               w += N_NODES*4;
  int* off  = (int*)w;                               w += N_NODES*4;
  int* curs = (int*)w;                               w += N_NODES*4;
  int* dste = (int*)w;                               w += N_EDGES*4;
  int* bsum = (int*)w;

  k_prep<<<(N_NODES+255)/256,256,0,stream>>>(W1,W2,W1t,W2t,cnt);

  int gemm_grid = (RTOT + 63)/64;
  k_gemm1_mfma<<<gemm_grid,256,0,stream>>>(h,W1t,a,g,s_i,s_j);

  k_hist<<<(N_EDGES+255)/256,256,0,stream>>>(src,cnt);
  int nb=(N_NODES+1023)/1024;
  k_scan_a<<<nb,1024,0,stream>>>(cnt,bsum);
  k_scan_b<<<1,64,0,stream>>>(bsum,nb);
  k_scan_c<<<nb,1024,0,stream>>>(cnt,bsum,off,curs);
  k_fill<<<(N_EDGES+255)/256,256,0,stream>>>(src,dst,curs,dste);

  k_agg<<<(N_NODES+3)/4,256,0,stream>>>((const unsigned int*)g,s_i,s_j,cnt,off,dste,(unsigned int*)hp);

  k_gemm2_mfma<<<gemm_grid,256,0,stream>>>(hp,W2t,out);
}

// Round 4
// 199.327 us; speedup vs baseline: 3.2132x; 1.0040x over previous
//
#include <hip/hip_runtime.h>
#include <hip/hip_bf16.h>
#include <cfloat>

#define N_NODES 50000
#define N_EDGES 800000
#define FEAT 128
#define BATCH 2
#define RTOT (BATCH*N_NODES)

typedef __bf16 bf16x8 __attribute__((ext_vector_type(8)));
typedef float  f32x4  __attribute__((ext_vector_type(4)));

__device__ inline unsigned short f2bf(float f){
  unsigned int u = __float_as_uint(f);
  u = (u + 0x7fffu + ((u >> 16) & 1u)) >> 16;
  return (unsigned short)u;
}

// ---- prep: W1t/W2t = bf16(W^T) pre-swizzled; also zero cnt ----
__global__ void k_prep(const float* __restrict__ W1, const float* __restrict__ W2,
                       __bf16* __restrict__ W1t, __bf16* __restrict__ W2t,
                       int* __restrict__ cnt){
  int i = blockIdx.x*blockDim.x + threadIdx.x;
  if(i < FEAT*FEAT){
    int k = i >> 7, col = i & 127;
    int sw = (col << 7) + (k ^ ((col & 7) << 3));
    W1t[sw] = (__bf16)W1[i];
    W2t[sw] = (__bf16)W2[i];
  }
  if(i < N_NODES) cnt[i] = 0;
}

// ---- GEMM1 (MFMA): g[n][b][128] = bf16(h @ W1), s_i/s_j[n][b] ----
__global__ __launch_bounds__(256) void k_gemm1_mfma(const float* __restrict__ h,
        const __bf16* __restrict__ W1t, const float* __restrict__ a,
        __bf16* __restrict__ g, float* __restrict__ s_i, float* __restrict__ s_j)
{
  __shared__ __bf16 Bs[FEAT*FEAT];   // 32KB swizzled W^T
  int t = threadIdx.x, lane = t & 63, wid = t >> 6;
  {
    const float4* srcp = (const float4*)W1t;
    float4* dstp = (float4*)Bs;
    for(int i = t; i < FEAT*FEAT/8; i += 256) dstp[i] = srcp[i];
  }
  __syncthreads();

  int rb = blockIdx.x*64 + wid*16;
  int r  = rb + (lane & 15);
  int kq = (lane >> 4) * 8;

  bf16x8 af[4];
  if(r < RTOT){
    const float* hrow = h + (size_t)r*FEAT + kq;
    #pragma unroll
    for(int ks = 0; ks < 4; ks++){
      float4 p0 = *(const float4*)(hrow + ks*32);
      float4 p1 = *(const float4*)(hrow + ks*32 + 4);
      bf16x8 v;
      v[0]=(__bf16)p0.x; v[1]=(__bf16)p0.y; v[2]=(__bf16)p0.z; v[3]=(__bf16)p0.w;
      v[4]=(__bf16)p1.x; v[5]=(__bf16)p1.y; v[6]=(__bf16)p1.z; v[7]=(__bf16)p1.w;
      af[ks] = v;
    }
  } else {
    #pragma unroll
    for(int ks = 0; ks < 4; ks++){ bf16x8 z = {}; af[ks] = z; }
  }

  f32x4 acc[8] = {};
  #pragma unroll
  for(int cb = 0; cb < 8; cb++){
    int col = cb*16 + (lane & 15);
    int swbase = (col << 7);
    int swx = ((col & 7) << 3);
    #pragma unroll
    for(int ks = 0; ks < 4; ks++){
      int kb = ks*32 + kq;
      bf16x8 bf = *(const bf16x8*)&Bs[swbase + (kb ^ swx)];
      acc[cb] = __builtin_amdgcn_mfma_f32_16x16x32_bf16(af[ks], bf, acc[cb], 0, 0, 0);
    }
  }

  int hgrp = lane >> 4;
  float pi[4] = {0,0,0,0}, pj[4] = {0,0,0,0};
  #pragma unroll
  for(int cb = 0; cb < 8; cb++){
    int col = cb*16 + (lane & 15);
    float al = a[col], ah = a[FEAT + col];
    #pragma unroll
    for(int reg = 0; reg < 4; reg++){
      int row = rb + hgrp*4 + reg;
      float v = acc[cb][reg];
      if(row < RTOT){
        int b = (row >= N_NODES) ? 1 : 0;
        int n = row - b*N_NODES;
        g[(size_t)n*256 + b*128 + col] = (__bf16)v;   // interleaved [n][b][128]
      }
      pi[reg] = fmaf(v, al, pi[reg]);
      pj[reg] = fmaf(v, ah, pj[reg]);
    }
  }
  #pragma unroll
  for(int reg = 0; reg < 4; reg++){
    #pragma unroll
    for(int m = 1; m < 16; m <<= 1){
      pi[reg] += __shfl_xor(pi[reg], m, 64);
      pj[reg] += __shfl_xor(pj[reg], m, 64);
    }
  }
  if((lane & 15) == 0){
    #pragma unroll
    for(int reg = 0; reg < 4; reg++){
      int row = rb + hgrp*4 + reg;
      if(row < RTOT){
        int b = (row >= N_NODES) ? 1 : 0;
        int n = row - b*N_NODES;
        s_i[n*2 + b] = pi[reg];
        s_j[n*2 + b] = pj[reg];
      }
    }
  }
}

// ---------------- CSR build over src ----------------
__global__ void k_hist(const int* __restrict__ src, int* __restrict__ cnt){
  int e = blockIdx.x*blockDim.x+threadIdx.x;
  if(e<N_EDGES) atomicAdd(&cnt[src[e]], 1);
}
__global__ __launch_bounds__(1024) void k_scan_a(const int* __restrict__ cnt, int* __restrict__ bsum){
  __shared__ int s[1024];
  int t=threadIdx.x; int idx = blockIdx.x*1024+t;
  s[t] = (idx<N_NODES)? cnt[idx] : 0;
  __syncthreads();
  for(int st=512; st>0; st>>=1){ if(t<st) s[t]+=s[t+st]; __syncthreads(); }
  if(t==0) bsum[blockIdx.x]=s[0];
}
__global__ void k_scan_b(int* __restrict__ bsum, int nb){   // 1 block, 64 threads
  int t=threadIdx.x;
  int v0 = (t<nb)? bsum[t] : 0;
  int v = v0;
  for(int st=1; st<64; st<<=1){
    int u = __shfl_up(v, st, 64);
    if(t>=st) v += u;
  }
  if(t<nb) bsum[t] = v - v0;   // exclusive
}
__global__ __launch_bounds__(1024) void k_scan_c(const int* __restrict__ cnt, const int* __restrict__ bsum,
                                                 int* __restrict__ off, int* __restrict__ curs){
  __shared__ int s[1024];
  int t=threadIdx.x; int idx=blockIdx.x*1024+t;
  int v=(idx<N_NODES)? cnt[idx]:0;
  s[t]=v; __syncthreads();
  for(int st=1; st<1024; st<<=1){
    int u = (t>=st)? s[t-st] : 0;
    __syncthreads();
    s[t] += u;
    __syncthreads();
  }
  if(idx<N_NODES){ int o = bsum[blockIdx.x] + s[t] - v; off[idx]=o; curs[idx]=o; }
}
// store dst VALUES in CSR order
__global__ void k_fill(const int* __restrict__ src, const int* __restrict__ dst,
                       int* __restrict__ curs, int* __restrict__ dste){
  int e=blockIdx.x*blockDim.x+threadIdx.x;
  if(e<N_EDGES){ int pos = atomicAdd(&curs[src[e]],1); dste[pos]=dst[e]; }
}

// ---- aggregate: one wave per node, both batches fused, online softmax ----
// lanes 0-31: batch0 (lane li covers feats 4*li..4*li+3); lanes 32-63: batch1.
// Gather loop unrolled x8; slots past deg have p=0,d=0 (row 0 is cache-hot, FMA adds 0).
__global__ __launch_bounds__(256) void k_agg(const unsigned int* __restrict__ g,
     const float* __restrict__ s_i, const float* __restrict__ s_j,
     const int* __restrict__ cnt, const int* __restrict__ off,
     const int* __restrict__ dste, unsigned int* __restrict__ hp)
{
  int widb = threadIdx.x>>6, lane = threadIdx.x&63;
  int n = blockIdx.x*4 + widb;
  if(n >= N_NODES) return;
  int deg = cnt[n], o0 = off[n];
  int half = lane >> 5, li = lane & 31;
  float si = s_i[n*2 + half];
  int selp = lane & 32;

  float m = -FLT_MAX, denom = 0.f;
  float a0=0.f, a1=0.f, a2=0.f, a3=0.f;

  for(int base=0; base<deg; base+=32){
    int i = base + li;
    int d = 0; float x = -FLT_MAX;
    if(i < deg){
      d = dste[o0 + i];                       // coalesced segment read
      float xx = si + s_j[d*2 + half];        // scattered 4B gather (L2-resident, 400KB)
      x = (xx > 0.f) ? xx : 0.2f*xx;
    }
    float cm = x;
    #pragma unroll
    for(int mm=16; mm; mm>>=1) cm = fmaxf(cm, __shfl_xor(cm, mm, 64));
    float mn = fmaxf(m, cm);
    float scale = __expf(m - mn);             // first chunk: exp(-inf)=0
    float p = (i < deg) ? __expf(x - mn) : 0.f;
    denom = denom*scale + p;
    a0*=scale; a1*=scale; a2*=scale; a3*=scale;
    m = mn;

    int lim = min(32, deg-base);
    int lim8 = (lim + 7) & ~7;
    for(int j=0; j<lim8; j+=8){
      float q[8]; int e[8];
      #pragma unroll
      for(int c=0;c<8;c++){
        q[c] = __shfl(p, selp | (j+c), 64);
        e[c] = __shfl(d, j+c, 64);
      }
      uint2 u[8];
      #pragma unroll
      for(int c=0;c<8;c++) u[c] = *(const uint2*)(g + (size_t)e[c]*128 + lane*2);
      #pragma unroll
      for(int c=0;c<8;c++){
        a0 = fmaf(q[c], __uint_as_float(u[c].x << 16),         a0);
        a1 = fmaf(q[c], __uint_as_float(u[c].x & 0xffff0000u), a1);
        a2 = fmaf(q[c], __uint_as_float(u[c].y << 16),         a2);
        a3 = fmaf(q[c], __uint_as_float(u[c].y & 0xffff0000u), a3);
      }
    }
  }
  #pragma unroll
  for(int mm=16; mm; mm>>=1) denom += __shfl_xor(denom, mm, 64);
  float inv = (denom > 0.f) ? 1.0f/denom : 0.f;
  unsigned int w0 = ((unsigned int)f2bf(a1*inv) << 16) | f2bf(a0*inv);
  unsigned int w1 = ((unsigned int)f2bf(a3*inv) << 16) | f2bf(a2*inv);
  uint2 o; o.x = w0; o.y = w1;
  *(uint2*)(hp + (size_t)n*128 + lane*2) = o;
}

// ---- GEMM2 (MFMA): out[b*N+n] = relu(hp_interleaved @ W2) ----
__global__ __launch_bounds__(256) void k_gemm2_mfma(const __bf16* __restrict__ hp,
        const __bf16* __restrict__ W2t, float* __restrict__ out)
{
  __shared__ __bf16 Bs[FEAT*FEAT];
  int t = threadIdx.x, lane = t & 63, wid = t >> 6;
  {
    const float4* srcp = (const float4*)W2t;
    float4* dstp = (float4*)Bs;
    for(int i = t; i < FEAT*FEAT/8; i += 256) dstp[i] = srcp[i];
  }
  __syncthreads();

  int rb = blockIdx.x*64 + wid*16;   // interleaved row index ri = n*2+b
  int r  = rb + (lane & 15);
  int kq = (lane >> 4) * 8;

  bf16x8 af[4];
  if(r < RTOT){
    const __bf16* hrow = hp + (size_t)r*FEAT + kq;
    #pragma unroll
    for(int ks = 0; ks < 4; ks++) af[ks] = *(const bf16x8*)(hrow + ks*32);
  } else {
    #pragma unroll
    for(int ks = 0; ks < 4; ks++){ bf16x8 z = {}; af[ks] = z; }
  }

  f32x4 acc[8] = {};
  #pragma unroll
  for(int cb = 0; cb < 8; cb++){
    int col = cb*16 + (lane & 15);
    int swbase = (col << 7);
    int swx = ((col & 7) << 3);
    #pragma unroll
    for(int ks = 0; ks < 4; ks++){
      int kb = ks*32 + kq;
      bf16x8 bf = *(const bf16x8*)&Bs[swbase + (kb ^ swx)];
      acc[cb] = __builtin_amdgcn_mfma_f32_16x16x32_bf16(af[ks], bf, acc[cb], 0, 0, 0);
    }
  }

  int hgrp = lane >> 4;
  #pragma unroll
  for(int cb = 0; cb < 8; cb++){
    int col = cb*16 + (lane & 15);
    #pragma unroll
    for(int reg = 0; reg < 4; reg++){
      int ri = rb + hgrp*4 + reg;
      if(ri < RTOT){
        int orow = (ri & 1)*N_NODES + (ri >> 1);   // de-interleave
        out[(size_t)orow*FEAT + col] = fmaxf(acc[cb][reg], 0.f);
      }
    }
  }
}

extern "C" void kernel_launch(void* const* d_in, const int* in_sizes, int n_in,
                              void* d_out, int out_size, void* d_ws, size_t ws_size,
                              hipStream_t stream) {
  const float* h  = (const float*)d_in[0];
  const float* W1 = (const float*)d_in[1];
  const float* W2 = (const float*)d_in[2];
  const float* a  = (const float*)d_in[3];
  const int* src  = (const int*)d_in[4];
  const int* dst  = (const int*)d_in[5];
  float* out = (float*)d_out;

  char* w = (char*)d_ws;
  __bf16* g   = (__bf16*)w;                          w += (size_t)RTOT*FEAT*2;   // 25.6MB interleaved
  __bf16* hp  = (__bf16*)w;                          w += (size_t)RTOT*FEAT*2;   // 25.6MB interleaved
  float* s_i  = (float*)w;                           w += (size_t)RTOT*4;
  float* s_j  = (float*)w;                           w += (size_t)RTOT*4;
  __bf16* W1t = (__bf16*)w;                          w += FEAT*FEAT*2;
  __bf16* W2t = (__bf16*)w;                          w += FEAT*FEAT*2;
  int* cnt  = (int*)w;                               w += N_NODES*4;
  int* off  = (int*)w;                               w += N_NODES*4;
  int* curs = (int*)w;                               w += N_NODES*4;
  int* dste = (int*)w;                               w += N_EDGES*4;
  int* bsum = (int*)w;

  k_prep<<<(N_NODES+255)/256,256,0,stream>>>(W1,W2,W1t,W2t,cnt);

  int gemm_grid = (RTOT + 63)/64;
  k_gemm1_mfma<<<gemm_grid,256,0,stream>>>(h,W1t,a,g,s_i,s_j);

  k_hist<<<(N_EDGES+255)/256,256,0,stream>>>(src,cnt);
  int nb=(N_NODES+1023)/1024;
  k_scan_a<<<nb,1024,0,stream>>>(cnt,bsum);
  k_scan_b<<<1,64,0,stream>>>(bsum,nb);
  k_scan_c<<<nb,1024,0,stream>>>(cnt,bsum,off,curs);
  k_fill<<<(N_EDGES+255)/256,256,0,stream>>>(src,dst,curs,dste);

  k_agg<<<(N_NODES+3)/4,256,0,stream>>>((const unsigned int*)g,s_i,s_j,cnt,off,dste,(unsigned int*)hp);

  k_gemm2_mfma<<<gemm_grid,256,0,stream>>>(hp,W2t,out);
}

// Round 5
// 181.723 us; speedup vs baseline: 3.5244x; 1.0969x over previous
//
#include <hip/hip_runtime.h>
#include <hip/hip_bf16.h>
#include <hip/hip_fp16.h>
#include <cfloat>

#define N_NODES 50000
#define N_EDGES 800000
#define FEAT 128
#define BATCH 2
#define RTOT (BATCH*N_NODES)

typedef __bf16 bf16x8 __attribute__((ext_vector_type(8)));
typedef float  f32x4  __attribute__((ext_vector_type(4)));

__device__ inline unsigned short f2bf(float f){
  unsigned int u = __float_as_uint(f);
  u = (u + 0x7fffu + ((u >> 16) & 1u)) >> 16;
  return (unsigned short)u;
}

// ---- prep: W1t/W2t = bf16(W^T) pre-swizzled; zero cnt ----
__global__ void k_prep(const float* __restrict__ W1, const float* __restrict__ W2,
                       __bf16* __restrict__ W1t, __bf16* __restrict__ W2t,
                       int* __restrict__ cnt){
  int i = blockIdx.x*blockDim.x + threadIdx.x;
  if(i < FEAT*FEAT){
    int k = i >> 7, col = i & 127;
    int sw = (col << 7) + (k ^ ((col & 7) << 3));
    W1t[sw] = (__bf16)W1[i];
    W2t[sw] = (__bf16)W2[i];
  }
  if(i < N_NODES) cnt[i] = 0;
}

// ---- GEMM1 (MFMA): g[n][b][128]=bf16(h@W1), s_i/s_j[n][b]; fused src-histogram ----
__global__ __launch_bounds__(256) void k_gemm1_mfma(const float* __restrict__ h,
        const __bf16* __restrict__ W1t, const float* __restrict__ a,
        __bf16* __restrict__ g, float* __restrict__ s_i, float* __restrict__ s_j,
        const int* __restrict__ src, int* __restrict__ cnt)
{
  __shared__ __bf16 Bs[FEAT*FEAT];   // 32KB swizzled W^T
  int t = threadIdx.x, lane = t & 63, wid = t >> 6;
  {
    const float4* srcp = (const float4*)W1t;
    float4* dstp = (float4*)Bs;
    for(int i = t; i < FEAT*FEAT/8; i += 256) dstp[i] = srcp[i];
  }
  __syncthreads();

  int rb = blockIdx.x*64 + wid*16;
  int r  = rb + (lane & 15);
  int kq = (lane >> 4) * 8;

  bf16x8 af[4];
  if(r < RTOT){
    const float* hrow = h + (size_t)r*FEAT + kq;
    #pragma unroll
    for(int ks = 0; ks < 4; ks++){
      float4 p0 = *(const float4*)(hrow + ks*32);
      float4 p1 = *(const float4*)(hrow + ks*32 + 4);
      bf16x8 v;
      v[0]=(__bf16)p0.x; v[1]=(__bf16)p0.y; v[2]=(__bf16)p0.z; v[3]=(__bf16)p0.w;
      v[4]=(__bf16)p1.x; v[5]=(__bf16)p1.y; v[6]=(__bf16)p1.z; v[7]=(__bf16)p1.w;
      af[ks] = v;
    }
  } else {
    #pragma unroll
    for(int ks = 0; ks < 4; ks++){ bf16x8 z = {}; af[ks] = z; }
  }

  f32x4 acc[8] = {};
  #pragma unroll
  for(int cb = 0; cb < 8; cb++){
    int col = cb*16 + (lane & 15);
    int swbase = (col << 7);
    int swx = ((col & 7) << 3);
    #pragma unroll
    for(int ks = 0; ks < 4; ks++){
      int kb = ks*32 + kq;
      bf16x8 bf = *(const bf16x8*)&Bs[swbase + (kb ^ swx)];
      acc[cb] = __builtin_amdgcn_mfma_f32_16x16x32_bf16(af[ks], bf, acc[cb], 0, 0, 0);
    }
  }

  int hgrp = lane >> 4;
  float pi[4] = {0,0,0,0}, pj[4] = {0,0,0,0};
  #pragma unroll
  for(int cb = 0; cb < 8; cb++){
    int col = cb*16 + (lane & 15);
    float al = a[col], ah = a[FEAT + col];
    #pragma unroll
    for(int reg = 0; reg < 4; reg++){
      int row = rb + hgrp*4 + reg;
      float v = acc[cb][reg];
      if(row < RTOT){
        int b = (row >= N_NODES) ? 1 : 0;
        int n = row - b*N_NODES;
        g[(size_t)n*256 + b*128 + col] = (__bf16)v;   // interleaved [n][b][128]
      }
      pi[reg] = fmaf(v, al, pi[reg]);
      pj[reg] = fmaf(v, ah, pj[reg]);
    }
  }
  #pragma unroll
  for(int reg = 0; reg < 4; reg++){
    #pragma unroll
    for(int m = 1; m < 16; m <<= 1){
      pi[reg] += __shfl_xor(pi[reg], m, 64);
      pj[reg] += __shfl_xor(pj[reg], m, 64);
    }
  }
  if((lane & 15) == 0){
    #pragma unroll
    for(int reg = 0; reg < 4; reg++){
      int row = rb + hgrp*4 + reg;
      if(row < RTOT){
        int b = (row >= N_NODES) ? 1 : 0;
        int n = row - b*N_NODES;
        s_i[n*2 + b] = pi[reg];
        s_j[n*2 + b] = pj[reg];
      }
    }
  }

  // fused histogram over src (cnt pre-zeroed by k_prep)
  int gs = gridDim.x * 256;
  for(int e = blockIdx.x*256 + t; e < N_EDGES; e += gs)
    atomicAdd(&cnt[src[e]], 1);
}

// ---- scan 1: block-local exclusive scan + block sums ----
__global__ __launch_bounds__(1024) void k_scan1(const int* __restrict__ cnt,
                                                int* __restrict__ off, int* __restrict__ bsum){
  __shared__ int s[1024];
  int t = threadIdx.x, idx = blockIdx.x*1024 + t;
  int v = (idx < N_NODES) ? cnt[idx] : 0;
  s[t] = v; __syncthreads();
  for(int st = 1; st < 1024; st <<= 1){
    int u = (t >= st) ? s[t-st] : 0;
    __syncthreads();
    s[t] += u;
    __syncthreads();
  }
  if(idx < N_NODES) off[idx] = s[t] - v;
  if(t == 1023) bsum[blockIdx.x] = s[t];
}
// ---- scan 2: add scanned block prefix; emit curs copy ----
__global__ __launch_bounds__(1024) void k_scan2(int* __restrict__ off,
                                                const int* __restrict__ bsum, int* __restrict__ curs){
  __shared__ int pfx;
  int t = threadIdx.x, idx = blockIdx.x*1024 + t;
  if(t < 64){
    int nb = (N_NODES + 1023)/1024;
    int v0 = (t < nb) ? bsum[t] : 0;
    int v = v0;
    for(int st = 1; st < 64; st <<= 1){
      int u = __shfl_up(v, st, 64);
      if(t >= st) v += u;
    }
    if(t == blockIdx.x) pfx = v - v0;   // exclusive prefix of this block
  }
  __syncthreads();
  if(idx < N_NODES){
    int o = off[idx] + pfx;
    off[idx] = o;
    curs[idx] = o;
  }
}
// ---- fill: dst values in CSR-by-src order ----
__global__ void k_fill(const int* __restrict__ src, const int* __restrict__ dst,
                       int* __restrict__ curs, int* __restrict__ dste){
  int e = blockIdx.x*blockDim.x + threadIdx.x;
  if(e < N_EDGES){ int pos = atomicAdd(&curs[src[e]], 1); dste[pos] = dst[e]; }
}

// ---- aggregate: one wave/node, batches fused, no-max softmax (|x|<~8 -> exp safe),
//      single packed shfl per edge: w = (f16(p)<<16) | d  (d < 65536) ----
__global__ __launch_bounds__(256) void k_agg(const unsigned int* __restrict__ g,
     const float* __restrict__ s_i, const float* __restrict__ s_j,
     const int* __restrict__ cnt, const int* __restrict__ off,
     const int* __restrict__ dste, unsigned int* __restrict__ hp)
{
  int widb = threadIdx.x>>6, lane = threadIdx.x&63;
  int n = blockIdx.x*4 + widb;
  if(n >= N_NODES) return;
  int deg = cnt[n], o0 = off[n];
  int half = lane >> 5, li = lane & 31;
  float si = s_i[n*2 + half];
  int selp = lane & 32;

  float denom = 0.f;
  float a0=0.f, a1=0.f, a2=0.f, a3=0.f;

  for(int base=0; base<deg; base+=32){
    int i = base + li;
    unsigned int w = 0;                       // p=0, d=0 for inactive slots
    if(i < deg){
      int d = dste[o0 + i];                   // coalesced
      float xx = si + s_j[d*2 + half];        // scattered 4B gather (L2-resident)
      float x = (xx > 0.f) ? xx : 0.2f*xx;
      float p = __expf(x);
      denom += p;
      w = ((unsigned int)__half_as_ushort(__float2half(p)) << 16) | (unsigned int)d;
    }
    int lim = min(32, deg-base);
    int lim8 = (lim + 7) & ~7;
    for(int j=0; j<lim8; j+=8){
      unsigned int ww[8];
      #pragma unroll
      for(int c=0;c<8;c++) ww[c] = __shfl(w, selp | (j+c), 64);
      uint2 u[8]; float q[8];
      #pragma unroll
      for(int c=0;c<8;c++){
        q[c] = __half2float(__ushort_as_half((unsigned short)(ww[c] >> 16)));
        u[c] = *(const uint2*)(g + (size_t)(ww[c] & 0xffffu)*128 + lane*2);
      }
      #pragma unroll
      for(int c=0;c<8;c++){
        a0 = fmaf(q[c], __uint_as_float(u[c].x << 16),         a0);
        a1 = fmaf(q[c], __uint_as_float(u[c].x & 0xffff0000u), a1);
        a2 = fmaf(q[c], __uint_as_float(u[c].y << 16),         a2);
        a3 = fmaf(q[c], __uint_as_float(u[c].y & 0xffff0000u), a3);
      }
    }
  }
  #pragma unroll
  for(int mm=16; mm; mm>>=1) denom += __shfl_xor(denom, mm, 64);  // per-half sum
  float inv = (denom > 0.f) ? 1.0f/denom : 0.f;
  unsigned int w0 = ((unsigned int)f2bf(a1*inv) << 16) | f2bf(a0*inv);
  unsigned int w1 = ((unsigned int)f2bf(a3*inv) << 16) | f2bf(a2*inv);
  uint2 o; o.x = w0; o.y = w1;
  *(uint2*)(hp + (size_t)n*128 + lane*2) = o;
}

// ---- GEMM2 (MFMA): out[b*N+n] = relu(hp_interleaved @ W2) ----
__global__ __launch_bounds__(256) void k_gemm2_mfma(const __bf16* __restrict__ hp,
        const __bf16* __restrict__ W2t, float* __restrict__ out)
{
  __shared__ __bf16 Bs[FEAT*FEAT];
  int t = threadIdx.x, lane = t & 63, wid = t >> 6;
  {
    const float4* srcp = (const float4*)W2t;
    float4* dstp = (float4*)Bs;
    for(int i = t; i < FEAT*FEAT/8; i += 256) dstp[i] = srcp[i];
  }
  __syncthreads();

  int rb = blockIdx.x*64 + wid*16;   // interleaved row index ri = n*2+b
  int r  = rb + (lane & 15);
  int kq = (lane >> 4) * 8;

  bf16x8 af[4];
  if(r < RTOT){
    const __bf16* hrow = hp + (size_t)r*FEAT + kq;
    #pragma unroll
    for(int ks = 0; ks < 4; ks++) af[ks] = *(const bf16x8*)(hrow + ks*32);
  } else {
    #pragma unroll
    for(int ks = 0; ks < 4; ks++){ bf16x8 z = {}; af[ks] = z; }
  }

  f32x4 acc[8] = {};
  #pragma unroll
  for(int cb = 0; cb < 8; cb++){
    int col = cb*16 + (lane & 15);
    int swbase = (col << 7);
    int swx = ((col & 7) << 3);
    #pragma unroll
    for(int ks = 0; ks < 4; ks++){
      int kb = ks*32 + kq;
      bf16x8 bf = *(const bf16x8*)&Bs[swbase + (kb ^ swx)];
      acc[cb] = __builtin_amdgcn_mfma_f32_16x16x32_bf16(af[ks], bf, acc[cb], 0, 0, 0);
    }
  }

  int hgrp = lane >> 4;
  #pragma unroll
  for(int cb = 0; cb < 8; cb++){
    int col = cb*16 + (lane & 15);
    #pragma unroll
    for(int reg = 0; reg < 4; reg++){
      int ri = rb + hgrp*4 + reg;
      if(ri < RTOT){
        int orow = (ri & 1)*N_NODES + (ri >> 1);   // de-interleave
        out[(size_t)orow*FEAT + col] = fmaxf(acc[cb][reg], 0.f);
      }
    }
  }
}

extern "C" void kernel_launch(void* const* d_in, const int* in_sizes, int n_in,
                              void* d_out, int out_size, void* d_ws, size_t ws_size,
                              hipStream_t stream) {
  const float* h  = (const float*)d_in[0];
  const float* W1 = (const float*)d_in[1];
  const float* W2 = (const float*)d_in[2];
  const float* a  = (const float*)d_in[3];
  const int* src  = (const int*)d_in[4];
  const int* dst  = (const int*)d_in[5];
  float* out = (float*)d_out;

  char* w = (char*)d_ws;
  __bf16* g   = (__bf16*)w;                          w += (size_t)RTOT*FEAT*2;   // 25.6MB interleaved
  __bf16* hp  = (__bf16*)w;                          w += (size_t)RTOT*FEAT*2;   // 25.6MB interleaved
  float* s_i  = (float*)w;                           w += (size_t)RTOT*4;
  float* s_j  = (float*)w;                           w += (size_t)RTOT*4;
  __bf16* W1t = (__bf16*)w;                          w += FEAT*FEAT*2;
  __bf16* W2t = (__bf16*)w;                          w += FEAT*FEAT*2;
  int* cnt  = (int*)w;                               w += N_NODES*4;
  int* off  = (int*)w;                               w += N_NODES*4;
  int* curs = (int*)w;                               w += N_NODES*4;
  int* dste = (int*)w;                               w += N_EDGES*4;
  int* bsum = (int*)w;

  k_prep<<<(N_NODES+255)/256,256,0,stream>>>(W1,W2,W1t,W2t,cnt);

  int gemm_grid = (RTOT + 63)/64;
  k_gemm1_mfma<<<gemm_grid,256,0,stream>>>(h,W1t,a,g,s_i,s_j,src,cnt);

  int nb = (N_NODES+1023)/1024;
  k_scan1<<<nb,1024,0,stream>>>(cnt,off,bsum);
  k_scan2<<<nb,1024,0,stream>>>(off,bsum,curs);
  k_fill<<<(N_EDGES+255)/256,256,0,stream>>>(src,dst,curs,dste);

  k_agg<<<(N_NODES+3)/4,256,0,stream>>>((const unsigned int*)g,s_i,s_j,cnt,off,dste,(unsigned int*)hp);

  k_gemm2_mfma<<<gemm_grid,256,0,stream>>>(hp,W2t,out);
}

// Round 6
// 166.407 us; speedup vs baseline: 3.8488x; 1.0920x over previous
//
#include <hip/hip_runtime.h>
#include <hip/hip_bf16.h>
#include <hip/hip_fp16.h>
#include <cfloat>

#define N_NODES 50000
#define N_EDGES 800000
#define FEAT 128
#define BATCH 2
#define RTOT (BATCH*N_NODES)

typedef __bf16 bf16x8 __attribute__((ext_vector_type(8)));
typedef float  f32x4  __attribute__((ext_vector_type(4)));

__device__ inline unsigned short f2bf(float f){
  unsigned int u = __float_as_uint(f);
  u = (u + 0x7fffu + ((u >> 16) & 1u)) >> 16;
  return (unsigned short)u;
}

// ---- prep: W1t/W2t = bf16(W^T) pre-swizzled; zero cnt ----
__global__ void k_prep(const float* __restrict__ W1, const float* __restrict__ W2,
                       __bf16* __restrict__ W1t, __bf16* __restrict__ W2t,
                       int* __restrict__ cnt){
  int i = blockIdx.x*blockDim.x + threadIdx.x;
  if(i < FEAT*FEAT){
    int k = i >> 7, col = i & 127;
    int sw = (col << 7) + (k ^ ((col & 7) << 3));
    W1t[sw] = (__bf16)W1[i];
    W2t[sw] = (__bf16)W2[i];
  }
  if(i < N_NODES) cnt[i] = 0;
}

// ---- GEMM1 (MFMA): g[n][b][128]=bf16(h@W1), s_i/s_j[n][b]; fused src-histogram ----
__global__ __launch_bounds__(256) void k_gemm1_mfma(const float* __restrict__ h,
        const __bf16* __restrict__ W1t, const float* __restrict__ a,
        __bf16* __restrict__ g, float* __restrict__ s_i, float* __restrict__ s_j,
        const int* __restrict__ src, int* __restrict__ cnt)
{
  __shared__ __bf16 Bs[FEAT*FEAT];   // 32KB swizzled W^T
  int t = threadIdx.x, lane = t & 63, wid = t >> 6;
  {
    const float4* srcp = (const float4*)W1t;
    float4* dstp = (float4*)Bs;
    for(int i = t; i < FEAT*FEAT/8; i += 256) dstp[i] = srcp[i];
  }
  __syncthreads();

  int rb = blockIdx.x*64 + wid*16;
  int r  = rb + (lane & 15);
  int kq = (lane >> 4) * 8;

  bf16x8 af[4];
  if(r < RTOT){
    const float* hrow = h + (size_t)r*FEAT + kq;
    #pragma unroll
    for(int ks = 0; ks < 4; ks++){
      float4 p0 = *(const float4*)(hrow + ks*32);
      float4 p1 = *(const float4*)(hrow + ks*32 + 4);
      bf16x8 v;
      v[0]=(__bf16)p0.x; v[1]=(__bf16)p0.y; v[2]=(__bf16)p0.z; v[3]=(__bf16)p0.w;
      v[4]=(__bf16)p1.x; v[5]=(__bf16)p1.y; v[6]=(__bf16)p1.z; v[7]=(__bf16)p1.w;
      af[ks] = v;
    }
  } else {
    #pragma unroll
    for(int ks = 0; ks < 4; ks++){ bf16x8 z = {}; af[ks] = z; }
  }

  f32x4 acc[8] = {};
  #pragma unroll
  for(int cb = 0; cb < 8; cb++){
    int col = cb*16 + (lane & 15);
    int swbase = (col << 7);
    int swx = ((col & 7) << 3);
    #pragma unroll
    for(int ks = 0; ks < 4; ks++){
      int kb = ks*32 + kq;
      bf16x8 bf = *(const bf16x8*)&Bs[swbase + (kb ^ swx)];
      acc[cb] = __builtin_amdgcn_mfma_f32_16x16x32_bf16(af[ks], bf, acc[cb], 0, 0, 0);
    }
  }

  int hgrp = lane >> 4;
  float pi[4] = {0,0,0,0}, pj[4] = {0,0,0,0};
  #pragma unroll
  for(int cb = 0; cb < 8; cb++){
    int col = cb*16 + (lane & 15);
    float al = a[col], ah = a[FEAT + col];
    #pragma unroll
    for(int reg = 0; reg < 4; reg++){
      int row = rb + hgrp*4 + reg;
      float v = acc[cb][reg];
      if(row < RTOT){
        int b = (row >= N_NODES) ? 1 : 0;
        int n = row - b*N_NODES;
        g[(size_t)n*256 + b*128 + col] = (__bf16)v;   // interleaved [n][b][128]
      }
      pi[reg] = fmaf(v, al, pi[reg]);
      pj[reg] = fmaf(v, ah, pj[reg]);
    }
  }
  #pragma unroll
  for(int reg = 0; reg < 4; reg++){
    #pragma unroll
    for(int m = 1; m < 16; m <<= 1){
      pi[reg] += __shfl_xor(pi[reg], m, 64);
      pj[reg] += __shfl_xor(pj[reg], m, 64);
    }
  }
  if((lane & 15) == 0){
    #pragma unroll
    for(int reg = 0; reg < 4; reg++){
      int row = rb + hgrp*4 + reg;
      if(row < RTOT){
        int b = (row >= N_NODES) ? 1 : 0;
        int n = row - b*N_NODES;
        s_i[n*2 + b] = pi[reg];
        s_j[n*2 + b] = pj[reg];
      }
    }
  }

  // fused histogram over src (cnt pre-zeroed by k_prep)
  int gs = gridDim.x * 256;
  for(int e = blockIdx.x*256 + t; e < N_EDGES; e += gs)
    atomicAdd(&cnt[src[e]], 1);
}

// ---- scan 1: block-local exclusive scan + block sums ----
__global__ __launch_bounds__(1024) void k_scan1(const int* __restrict__ cnt,
                                                int* __restrict__ off, int* __restrict__ bsum){
  __shared__ int s[1024];
  int t = threadIdx.x, idx = blockIdx.x*1024 + t;
  int v = (idx < N_NODES) ? cnt[idx] : 0;
  s[t] = v; __syncthreads();
  for(int st = 1; st < 1024; st <<= 1){
    int u = (t >= st) ? s[t-st] : 0;
    __syncthreads();
    s[t] += u;
    __syncthreads();
  }
  if(idx < N_NODES) off[idx] = s[t] - v;
  if(t == 1023) bsum[blockIdx.x] = s[t];
}
// ---- scan 2: add scanned block prefix; emit curs copy ----
__global__ __launch_bounds__(1024) void k_scan2(int* __restrict__ off,
                                                const int* __restrict__ bsum, int* __restrict__ curs){
  __shared__ int pfx;
  int t = threadIdx.x, idx = blockIdx.x*1024 + t;
  if(t < 64){
    int nb = (N_NODES + 1023)/1024;
    int v0 = (t < nb) ? bsum[t] : 0;
    int v = v0;
    for(int st = 1; st < 64; st <<= 1){
      int u = __shfl_up(v, st, 64);
      if(t >= st) v += u;
    }
    if(t == blockIdx.x) pfx = v - v0;   // exclusive prefix of this block
  }
  __syncthreads();
  if(idx < N_NODES){
    int o = off[idx] + pfx;
    off[idx] = o;
    curs[idx] = o;
  }
}
// ---- fill: dst values in CSR-by-src order ----
__global__ void k_fill(const int* __restrict__ src, const int* __restrict__ dst,
                       int* __restrict__ curs, int* __restrict__ dste){
  int e = blockIdx.x*blockDim.x + threadIdx.x;
  if(e < N_EDGES){ int pos = atomicAdd(&curs[src[e]], 1); dste[pos] = dst[e]; }
}

// ---- FUSED aggregate + GEMM2: block = 8 waves = 8 nodes -> 16-row MFMA tile ----
// Agg: lanes 0-31 batch0, 32-63 batch1; lane li covers feats 4*li..4*li+3.
// hpT LDS tile swizzled on 8-elem granule: granule ^= (row&7)  (conflict-free b128 reads).
__global__ __launch_bounds__(512) void k_agg2(const unsigned int* __restrict__ g,
     const float* __restrict__ s_i, const float* __restrict__ s_j,
     const int* __restrict__ cnt, const int* __restrict__ off,
     const int* __restrict__ dste, const __bf16* __restrict__ W2t,
     float* __restrict__ out)
{
  __shared__ __bf16 Bs[FEAT*FEAT];    // 32KB swizzled W2^T
  __shared__ __bf16 hpT[16*FEAT];     // 4KB swizzled A-tile (16 rows = 8 nodes x 2 batches)
  int t = threadIdx.x, lane = t & 63, w = t >> 6;
  {
    const float4* srcp = (const float4*)W2t;
    float4* dstp = (float4*)Bs;
    for(int i = t; i < FEAT*FEAT/8; i += 512) dstp[i] = srcp[i];
  }

  // ---- aggregation phase (one wave per node) ----
  int n = blockIdx.x*8 + w;           // N_NODES = 8*6250 exactly
  int deg = cnt[n], o0 = off[n];
  int half = lane >> 5, li = lane & 31;
  float si = s_i[n*2 + half];
  int selp = lane & 32;

  float denom = 0.f;
  float a0=0.f, a1=0.f, a2=0.f, a3=0.f;

  for(int base=0; base<deg; base+=32){
    int i = base + li;
    unsigned int wv = 0;                      // p=0, d=0 for inactive slots
    if(i < deg){
      int d = dste[o0 + i];                   // coalesced
      float xx = si + s_j[d*2 + half];        // scattered 4B gather (L2-resident)
      float x = (xx > 0.f) ? xx : 0.2f*xx;
      float p = __expf(x);                    // |x| small: no-max softmax is exact
      denom += p;
      wv = ((unsigned int)__half_as_ushort(__float2half(p)) << 16) | (unsigned int)d;
    }
    int lim = min(32, deg-base);
    int lim8 = (lim + 7) & ~7;
    for(int j=0; j<lim8; j+=8){
      unsigned int ww[8];
      #pragma unroll
      for(int c=0;c<8;c++) ww[c] = __shfl(wv, selp | (j+c), 64);
      uint2 u[8]; float q[8];
      #pragma unroll
      for(int c=0;c<8;c++){
        q[c] = __half2float(__ushort_as_half((unsigned short)(ww[c] >> 16)));
        u[c] = *(const uint2*)(g + (size_t)(ww[c] & 0xffffu)*128 + lane*2);
      }
      #pragma unroll
      for(int c=0;c<8;c++){
        a0 = fmaf(q[c], __uint_as_float(u[c].x << 16),         a0);
        a1 = fmaf(q[c], __uint_as_float(u[c].x & 0xffff0000u), a1);
        a2 = fmaf(q[c], __uint_as_float(u[c].y << 16),         a2);
        a3 = fmaf(q[c], __uint_as_float(u[c].y & 0xffff0000u), a3);
      }
    }
  }
  #pragma unroll
  for(int mm=16; mm; mm>>=1) denom += __shfl_xor(denom, mm, 64);  // per-half sum
  float inv = (denom > 0.f) ? 1.0f/denom : 0.f;

  // write hp row into swizzled LDS tile
  {
    int ri = w*2 + half;                 // tile row (interleaved node,batch)
    int gidx = li >> 1;                  // 8-elem granule index of col 4*li
    int gsw = gidx ^ (ri & 7);
    int coff = gsw*8 + (li & 1)*4;
    unsigned int w0 = ((unsigned int)f2bf(a1*inv) << 16) | f2bf(a0*inv);
    unsigned int w1 = ((unsigned int)f2bf(a3*inv) << 16) | f2bf(a2*inv);
    uint2 o; o.x = w0; o.y = w1;
    *(uint2*)&hpT[ri*FEAT + coff] = o;
  }
  __syncthreads();

  // ---- GEMM2 phase: 16x128 tile @ W2 (wave w -> col block w) ----
  int r  = lane & 15;
  int kq16 = lane >> 4;                  // 0..3
  bf16x8 af[4];
  #pragma unroll
  for(int ks = 0; ks < 4; ks++){
    int gr = ks*4 + kq16;                // granule index along K
    int gsw2 = gr ^ (r & 7);
    af[ks] = *(const bf16x8*)&hpT[r*FEAT + gsw2*8];
  }
  f32x4 acc = {};
  int col = w*16 + (lane & 15);
  int swbase = (col << 7);
  int swx = ((col & 7) << 3);
  #pragma unroll
  for(int ks = 0; ks < 4; ks++){
    int kb = ks*32 + kq16*8;
    bf16x8 bf = *(const bf16x8*)&Bs[swbase + (kb ^ swx)];
    acc = __builtin_amdgcn_mfma_f32_16x16x32_bf16(af[ks], bf, acc, 0, 0, 0);
  }
  int hgrp = lane >> 4;
  #pragma unroll
  for(int reg = 0; reg < 4; reg++){
    int rri = hgrp*4 + reg;
    int node = blockIdx.x*8 + (rri >> 1);
    int b = rri & 1;
    out[(size_t)(b*N_NODES + node)*FEAT + col] = fmaxf(acc[reg], 0.f);
  }
}

extern "C" void kernel_launch(void* const* d_in, const int* in_sizes, int n_in,
                              void* d_out, int out_size, void* d_ws, size_t ws_size,
                              hipStream_t stream) {
  const float* h  = (const float*)d_in[0];
  const float* W1 = (const float*)d_in[1];
  const float* W2 = (const float*)d_in[2];
  const float* a  = (const float*)d_in[3];
  const int* src  = (const int*)d_in[4];
  const int* dst  = (const int*)d_in[5];
  float* out = (float*)d_out;

  char* w = (char*)d_ws;
  __bf16* g   = (__bf16*)w;                          w += (size_t)RTOT*FEAT*2;   // 25.6MB interleaved
  float* s_i  = (float*)w;                           w += (size_t)RTOT*4;
  float* s_j  = (float*)w;                           w += (size_t)RTOT*4;
  __bf16* W1t = (__bf16*)w;                          w += FEAT*FEAT*2;
  __bf16* W2t = (__bf16*)w;                          w += FEAT*FEAT*2;
  int* cnt  = (int*)w;                               w += N_NODES*4;
  int* off  = (int*)w;                               w += N_NODES*4;
  int* curs = (int*)w;                               w += N_NODES*4;
  int* dste = (int*)w;                               w += N_EDGES*4;
  int* bsum = (int*)w;

  k_prep<<<(N_NODES+255)/256,256,0,stream>>>(W1,W2,W1t,W2t,cnt);

  int gemm_grid = (RTOT + 63)/64;
  k_gemm1_mfma<<<gemm_grid,256,0,stream>>>(h,W1t,a,g,s_i,s_j,src,cnt);

  int nb = (N_NODES+1023)/1024;
  k_scan1<<<nb,1024,0,stream>>>(cnt,off,bsum);
  k_scan2<<<nb,1024,0,stream>>>(off,bsum,curs);
  k_fill<<<(N_EDGES+255)/256,256,0,stream>>>(src,dst,curs,dste);

  k_agg2<<<N_NODES/8,512,0,stream>>>((const unsigned int*)g,s_i,s_j,cnt,off,dste,W2t,out);
}